// Round 6
// baseline (2004.801 us; speedup 1.0000x reference)
//
#include <hip/hip_runtime.h>

// GCN(3 layers) + MLP(4 layers), N=50000, E=800000, out = N x 8 bf16.
// NOTE: do NOT include <hip/hip_bf16.h> — it breaks this harness's build
// (rounds 1-4 silently fell back to a stub; round 5 proved it by dropping
// the include and getting real output). Manual bf16 via ushort bit ops.
// Dtype handling: runtime-detected, decoupled flags:
//   flagI: edge_index int64 vs int32 (odd int32 words all-zero => int64)
//   flagF: float tensors fp32 vs packed bf16 (exponent-field histogram of
//          EVEN uint16 words of x: bf16 => ~256/256 in [90,150]; fp32 =>
//          those are low mantissa halves, uniform => ~61/256)
// All internal math fp32.

#define GN 50000
#define GE 800000

__device__ __forceinline__ float ar1_b2f(unsigned short h) {
    return __uint_as_float(((unsigned)h) << 16);
}
__device__ __forceinline__ unsigned short ar1_f2b(float f) {
    unsigned u = __float_as_uint(f);
    u = u + 0x7FFFu + ((u >> 16) & 1u);   // round-to-nearest-even
    return (unsigned short)(u >> 16);
}

__global__ void ar1_zero(int* p, int n) {
    int i = blockIdx.x * 256 + threadIdx.x;
    if (i < n) p[i] = 0;
}

// flagI[0]=1 => edge_index is int64
__global__ void ar1_detect_idx(const int* ei, int* flagI) {
    __shared__ int cnt;
    if (threadIdx.x == 0) cnt = 0;
    __syncthreads();
    if (ei[2 * threadIdx.x + 1] != 0) atomicAdd(&cnt, 1);
    __syncthreads();
    if (threadIdx.x == 0) flagI[0] = (cnt < 8) ? 1 : 0;
}

// flagF[0]=1 => float tensors are fp32; 0 => packed bf16.
// Even-indexed uint16 words: bf16 elements (if bf16) vs low fp32 mantissa
// halves (if fp32). Exponent-like field in [90,150] or zero-word => "bf16ish".
__global__ void ar1_detect_f(const unsigned short* xw, int* flagF) {
    __shared__ int cnt;
    if (threadIdx.x == 0) cnt = 0;
    __syncthreads();
    unsigned short w = xw[2 * threadIdx.x];
    int ex = (w >> 7) & 0xFF;
    if (w == 0 || (ex >= 90 && ex <= 150)) atomicAdd(&cnt, 1);
    __syncthreads();
    if (threadIdx.x == 0) flagF[0] = (cnt > 200) ? 0 : 1;
}

__global__ void ar1_count(const int* ei, const int* flagI, int* indeg, int E) {
    int e = blockIdx.x * 256 + threadIdx.x;
    if (e < E) {
        int d = flagI[0] ? ei[2 * (E + e)] : ei[E + e];
        if ((unsigned)d < (unsigned)GN) atomicAdd(&indeg[d], 1);
    }
}

__global__ void ar1_scan1(const int* indeg, int* offsets, int* blksum, int n) {
    __shared__ int sm[256];
    int tid = threadIdx.x;
    int i = blockIdx.x * 256 + tid;
    int v = (i < n) ? indeg[i] : 0;
    sm[tid] = v;
    __syncthreads();
    for (int off = 1; off < 256; off <<= 1) {
        int t = (tid >= off) ? sm[tid - off] : 0;
        __syncthreads();
        sm[tid] += t;
        __syncthreads();
    }
    if (i < n) offsets[i] = sm[tid] - v;
    if (tid == 255) blksum[blockIdx.x] = sm[255];
}

__global__ void ar1_scan2(const int* blksum, int* blkbase, int nb) {
    __shared__ int sm[256];
    int tid = threadIdx.x;
    int v = (tid < nb) ? blksum[tid] : 0;
    sm[tid] = v;
    __syncthreads();
    for (int off = 1; off < 256; off <<= 1) {
        int t = (tid >= off) ? sm[tid - off] : 0;
        __syncthreads();
        sm[tid] += t;
        __syncthreads();
    }
    if (tid < nb) blkbase[tid] = sm[tid] - v;
}

__global__ void ar1_scan3(const int* indeg, int* offsets, int* cursor,
                          const int* blkbase, float* dinv, int n) {
    int i = blockIdx.x * 256 + threadIdx.x;
    if (i < n) {
        int o = offsets[i] + blkbase[blockIdx.x];
        offsets[i] = o;
        cursor[i] = o;
        dinv[i] = rsqrtf((float)(indeg[i] + 1));   // +1: self loop
    }
}

__global__ void ar1_fill(const int* ei, const int* flagI, int* cursor,
                         int* csr, int E) {
    int e = blockIdx.x * 256 + threadIdx.x;
    if (e < E) {
        int is64 = flagI[0];
        int s = is64 ? ei[2 * e] : ei[e];
        int d = is64 ? ei[2 * (E + e)] : ei[E + e];
        if ((unsigned)s < (unsigned)GN && (unsigned)d < (unsigned)GN) {
            int p = atomicAdd(&cursor[d], 1);
            csr[p] = s;
        }
    }
}

// convert float tensor (fp32 or packed-bf16, per flagF) to fp32
__global__ void ar1_cvt(const void* src, float* dst, int n, const int* flagF) {
    int i = blockIdx.x * 256 + threadIdx.x;
    if (i < n) {
        if (flagF[0]) dst[i] = ((const float*)src)[i];
        else          dst[i] = ar1_b2f(((const unsigned short*)src)[i]);
    }
}

// C[GN,M] = A[GN,K] @ W[K,M] (+bias)(+relu); wave-per-row
__global__ void ar1_gemm(const float* A, const float* W, const float* bias,
                         float* C, int K, int M, int relu) {
    int wid = (int)((blockIdx.x * 256u + threadIdx.x) >> 6);
    int lane = (int)(threadIdx.x & 63u);
    if (wid >= GN) return;
    const float* Ar = A + (size_t)wid * K;
    float acc[4];
    acc[0] = 0.f; acc[1] = 0.f; acc[2] = 0.f; acc[3] = 0.f;
    for (int k = 0; k < K; k++) {
        float a = Ar[k];
        const float* Wr = W + (size_t)k * M;
        int j = lane;
        acc[0] += a * Wr[j];
        j += 64; if (j < M) acc[1] += a * Wr[j];
        j += 64; if (j < M) acc[2] += a * Wr[j];
        j += 64; if (j < M) acc[3] += a * Wr[j];
    }
    for (int t = 0; t < 4; t++) {
        int j = t * 64 + lane;
        if (j < M) {
            float v = acc[t];
            if (bias) v += bias[j];
            if (relu) v = fmaxf(v, 0.f);
            C[(size_t)wid * M + j] = v;
        }
    }
}

// GCN aggregate (96 feats) + bias + BN(eval) + ReLU
__global__ void ar1_agg(const float* H, const int* offsets, const int* indeg,
                        const int* csr, const float* dinv,
                        const float* bias, const float* gamma, const float* beta,
                        float* Out) {
    __shared__ int   s_src[128];
    __shared__ float s_w[128];
    int node = blockIdx.x;
    int tid = threadIdx.x;
    float di = dinv[node];
    int off = offsets[node];
    int cnt = indeg[node];
    float acc = 0.f;
    for (int base = 0; base < cnt; base += 128) {
        int m = cnt - base;
        if (m > 128) m = 128;
        if (tid < m) {
            int s = csr[off + base + tid];
            if ((unsigned)s >= (unsigned)GN) s = node;
            s_src[tid] = s;
            s_w[tid] = dinv[s] * di;
        }
        __syncthreads();
        if (tid < 96) {
            for (int e = 0; e < m; e++)
                acc += s_w[e] * H[(size_t)s_src[e] * 96 + tid];
        }
        __syncthreads();
    }
    if (tid < 96) {
        acc += di * di * H[(size_t)node * 96 + tid];   // self loop
        float v = acc + bias[tid];
        v = v * 0.9999950000374997f * gamma[tid] + beta[tid];  // 1/sqrt(1+1e-5)
        Out[(size_t)node * 96 + tid] = fmaxf(v, 0.f);
    }
}

// final 64->8 layer: writes fp32 or bf16 per flagF
__global__ void Arthur1_16458314678864_kernel(const float* A, const float* W,
                                              const float* bias, void* out,
                                              const int* flagF) {
    int i = blockIdx.x * 256 + threadIdx.x;
    if (i >= GN * 8) return;
    int node = i >> 3;
    int j = i & 7;
    const float* Ar = A + (size_t)node * 64;
    float v = bias[j];
    for (int k = 0; k < 64; k++) v += Ar[k] * W[k * 8 + j];
    if (flagF[0]) ((float*)out)[i] = v;
    else ((unsigned short*)out)[i] = ar1_f2b(v);
}

extern "C" void kernel_launch(void* const* d_in, const int* in_sizes, int n_in,
                              void* d_out, int out_size, void* d_ws, size_t ws_size,
                              hipStream_t stream) {
    (void)in_sizes; (void)n_in; (void)out_size;

    // workspace layout
    char* p = (char*)d_ws;
    float* bufB = (float*)p;  p += (size_t)GN * 256 * 4;
    float* bufA = (float*)p;  p += (size_t)GN * 128 * 4;
    int* indeg  = (int*)p;    p += (size_t)GN * 4;
    int* offs   = (int*)p;    p += (size_t)GN * 4;
    int* cursor = (int*)p;    p += (size_t)GN * 4;
    int* blksum = (int*)p;    p += 1024;
    int* blkbase= (int*)p;    p += 1024;
    int* flagI  = (int*)p;    p += 1024;
    int* flagF  = (int*)p;    p += 1024;
    float* dinv = (float*)p;  p += (size_t)GN * 4;
    int* csr    = (int*)p;    p += (size_t)GE * 4;
    float* war  = (float*)p;  p += (size_t)92000 * 4;
    size_t need = (size_t)(p - (char*)d_ws);
    if (ws_size < need) {
        // marker: ws too small -> bf16 0x4141 = 12.0625 everywhere
        hipMemsetAsync(d_out, 0x41, (size_t)GN * 8 * 2, stream);
        return;
    }

    // converted-weight arena
    int wn[20] = {6144, 96, 96, 96, 9216, 96, 96, 96, 9216, 96, 96, 96,
                  24576, 256, 32768, 128, 8192, 64, 512, 8};
    float* wd[20];
    {
        float* q = war;
        for (int i = 0; i < 20; i++) { wd[i] = q; q += wn[i]; }
    }

    const int* ei = (const int*)d_in[1];
    const int NB = (GN + 255) / 256;
    const int EB = (GE + 255) / 256;

    ar1_detect_idx<<<1, 256, 0, stream>>>(ei, flagI);
    ar1_detect_f<<<1, 256, 0, stream>>>((const unsigned short*)d_in[0], flagF);
    ar1_zero<<<NB, 256, 0, stream>>>(indeg, GN);
    ar1_count<<<EB, 256, 0, stream>>>(ei, flagI, indeg, GE);
    ar1_scan1<<<NB, 256, 0, stream>>>(indeg, offs, blksum, GN);
    ar1_scan2<<<1, 256, 0, stream>>>(blksum, blkbase, NB);
    ar1_scan3<<<NB, 256, 0, stream>>>(indeg, offs, cursor, blkbase, dinv, GN);
    ar1_fill<<<EB, 256, 0, stream>>>(ei, flagI, cursor, csr, GE);

    ar1_cvt<<<(GN * 64 + 255) / 256, 256, 0, stream>>>(d_in[0], bufA, GN * 64, flagF);
    for (int i = 0; i < 20; i++)
        ar1_cvt<<<(wn[i] + 255) / 256, 256, 0, stream>>>(d_in[2 + i], wd[i], wn[i], flagF);

    const int GB = (GN + 3) / 4;   // 4 rows (waves) per 256-thread block

    // GCN 1..3
    ar1_gemm<<<GB, 256, 0, stream>>>(bufA, wd[0], (const float*)0, bufB, 64, 96, 0);
    ar1_agg<<<GN, 128, 0, stream>>>(bufB, offs, indeg, csr, dinv, wd[1], wd[2], wd[3], bufA);
    ar1_gemm<<<GB, 256, 0, stream>>>(bufA, wd[4], (const float*)0, bufB, 96, 96, 0);
    ar1_agg<<<GN, 128, 0, stream>>>(bufB, offs, indeg, csr, dinv, wd[5], wd[6], wd[7], bufA);
    ar1_gemm<<<GB, 256, 0, stream>>>(bufA, wd[8], (const float*)0, bufB, 96, 96, 0);
    ar1_agg<<<GN, 128, 0, stream>>>(bufB, offs, indeg, csr, dinv, wd[9], wd[10], wd[11], bufA);

    // MLP: 96->256->128->64->8
    ar1_gemm<<<GB, 256, 0, stream>>>(bufA, wd[12], wd[13], bufB, 96, 256, 1);
    ar1_gemm<<<GB, 256, 0, stream>>>(bufB, wd[14], wd[15], bufA, 256, 128, 1);
    ar1_gemm<<<GB, 256, 0, stream>>>(bufA, wd[16], wd[17], bufB, 128, 64, 1);
    Arthur1_16458314678864_kernel<<<(GN * 8 + 255) / 256, 256, 0, stream>>>(
        bufB, wd[18], wd[19], d_out, flagF);
}